// Round 11
// baseline (97.379 us; speedup 1.0000x reference)
//
#include <hip/hip_runtime.h>

#define IMG_H 768
#define IMG_W 768
#define N_IMG 32
#define TILE 64
#define HALO 2
#define LW 68              // 64 + 2*HALO
#define INV_LOG2 1.44269504088896340736f
#define TILES_X 12
#define TILES_PER_IMG 144
#define NTILES (N_IMG * TILES_PER_IMG)   // 4608
#define GRID1 1536                        // 3 tiles per block, exact

__device__ __forceinline__ float fast_sigmoid(float y) {
    return 1.0f / (1.0f + __expf(-y));
}

// Persistent 3-tile blocks with cross-tile software pipelining:
//   - y(t+1) prefetched into regs during tile t (hidden under full tile)
//   - gt(t) loads issued before the barrier, consumed after
//   - halo y(t) loaded into regs first, converted after the own-block phase
__global__ __launch_bounds__(256) void wk_pass1(
    const float* __restrict__ y_d, const float* __restrict__ y_gt,
    float* __restrict__ out, float* __restrict__ sums)
{
    __shared__ float pbuf[LW * LW];   // 18.5 KB
    __shared__ float red[4];

    const int tid = threadIdx.x;
    const int c0 = (tid & 15) << 2;    // tile col base 0..60
    const int rb = (tid >> 4) << 2;    // tile row base 0..60

    // ---- prologue: coords + y loads for first tile ----
    int tile = blockIdx.x;
    int img = tile / TILES_PER_IMG;
    int tt  = tile - img * TILES_PER_IMG;
    int ti  = tt / TILES_X;
    int tj  = tt - ti * TILES_X;
    int gi0 = ti * TILE, gj0 = tj * TILE;

    float4 ycur[4];
    {
        const float* __restrict__ yimg = y_d + (size_t)img * IMG_H * IMG_W;
#pragma unroll
        for (int r = 0; r < 4; ++r)
            ycur[r] = *reinterpret_cast<const float4*>(
                &yimg[(size_t)(gi0 + rb + r) * IMG_W + gj0 + c0]);
    }

    for (int it = 0; it < 3; ++it) {
        const size_t img_off = (size_t)img * IMG_H * IMG_W;
        const float* __restrict__ yimg = y_d + img_off;
        const float* __restrict__ gimg = y_gt + img_off;
        float* __restrict__ oimg = out + img_off;
        const int gj = gj0 + c0;

        // ---- 1. issue halo y loads into regs (3 slots cover 528 px) ----
        // OOB -> 0.0 later (the analytic C-1 normalization needs p=0 there).
        float hraw[3]; int hpr[3], hpc[3]; bool hact[3], hval[3];
#pragma unroll
        for (int k = 0; k < 3; ++k) {
            int idx = tid + (k << 8);
            hact[k] = idx < 528;
            int pr, pc;
            if (idx < 272) {
                int rsel = idx / 68;
                pr = (rsel < 2) ? rsel : (64 + rsel);    // 0,1,66,67
                pc = idx - rsel * 68;
            } else {
                int kk = idx - 272;
                pr = (kk >> 2) + 2;                      // 2..65
                int h = kk & 3;
                pc = (h < 2) ? h : (64 + h);             // 0,1,66,67
            }
            int gi_ = gi0 - HALO + pr;
            int gj_ = gj0 - HALO + pc;
            hval[k] = hact[k] && (unsigned)gi_ < (unsigned)IMG_H
                              && (unsigned)gj_ < (unsigned)IMG_W;
            hraw[k] = hval[k] ? yimg[(size_t)gi_ * IMG_W + gj_] : 0.0f;
            hpr[k] = pr; hpc[k] = pc;
        }

        // ---- 2. issue gt loads now; consumed after the barrier ----
        float4 gv4[4];
#pragma unroll
        for (int r = 0; r < 4; ++r)
            gv4[r] = *reinterpret_cast<const float4*>(
                &gimg[(size_t)(gi0 + rb + r) * IMG_W + gj]);

        // ---- 3. own 4x4 block: p/ent from ycur regs; p -> pbuf ----
        // ent = 1 + (p*y - softplus(y))/ln2; softplus shares exp with sigmoid.
        float4 pv4[4], ev4[4];
#pragma unroll
        for (int r = 0; r < 4; ++r) {
            float yy[4] = {ycur[r].x, ycur[r].y, ycur[r].z, ycur[r].w};
            float pp[4], ee[4];
#pragma unroll
            for (int u = 0; u < 4; ++u) {
                float y  = yy[u];
                float E  = __expf(-fabsf(y));
                float t2 = 1.0f + E;
                float rr = __fdividef(1.0f, t2);
                float p  = (y >= 0.0f) ? rr : E * rr;
                float sp = fmaxf(y, 0.0f) + __logf(t2);
                pp[u] = p;
                ee[u] = fmaf(fmaf(p, y, -sp), INV_LOG2, 1.0f);
            }
            pv4[r] = make_float4(pp[0], pp[1], pp[2], pp[3]);
            ev4[r] = make_float4(ee[0], ee[1], ee[2], ee[3]);
            *reinterpret_cast<float4*>(
                &pbuf[(rb + HALO + r) * LW + (c0 + HALO)]) = pv4[r];
        }

        // ---- 4. halo convert + write (loads issued in step 1) ----
#pragma unroll
        for (int k = 0; k < 3; ++k) {
            if (hact[k]) {
                float p = hval[k] ? fast_sigmoid(hraw[k]) : 0.0f;
                pbuf[hpr[k] * LW + hpc[k]] = p;
            }
        }

        // ---- 5. prefetch next tile's y into regs (consumed next iter) ----
        int ntile = tile + GRID1;
        int nimg = 0, ngi0 = 0, ngj0 = 0;
        if (it < 2) {
            nimg = ntile / TILES_PER_IMG;
            int nt = ntile - nimg * TILES_PER_IMG;
            int nti = nt / TILES_X;
            int ntj = nt - nti * TILES_X;
            ngi0 = nti * TILE; ngj0 = ntj * TILE;
            const float* __restrict__ yimg2 = y_d + (size_t)nimg * IMG_H * IMG_W;
            float4 ynxt[4];
#pragma unroll
            for (int r = 0; r < 4; ++r)
                ynxt[r] = *reinterpret_cast<const float4*>(
                    &yimg2[(size_t)(ngi0 + rb + r) * IMG_W + ngj0 + c0]);
#pragma unroll
            for (int r = 0; r < 4; ++r) ycur[r] = ynxt[r];
        }

        __syncthreads();

        // ---- 6. compute: vertical sliding 5-row window, cols c0..c0+7 ----
        float cxv[4], rcp5[4];
#pragma unroll
        for (int c = 0; c < 4; ++c) {
            int g = gj + c;
            cxv[c] = (float)(min(g, HALO) + min(IMG_W - 1 - g, HALO) + 1);
            rcp5[c] = __fdividef(1.0f, fmaf(5.0f, cxv[c], -1.0f)); // cy=5
        }

        float V1[8], V2[8];
#pragma unroll
        for (int cc = 0; cc < 8; ++cc) { V1[cc] = 0.f; V2[cc] = 0.f; }
#pragma unroll
        for (int k = 0; k < 5; ++k) {
            const float* row = &pbuf[(rb + k) * LW + c0];
            float4 A = *reinterpret_cast<const float4*>(row);
            float4 B = *reinterpret_cast<const float4*>(row + 4);
            float a[8] = {A.x, A.y, A.z, A.w, B.x, B.y, B.z, B.w};
#pragma unroll
            for (int cc = 0; cc < 8; ++cc) {
                V1[cc] += a[cc];
                V2[cc] = fmaf(a[cc], a[cc], V2[cc]);
            }
        }

        float lsum = 0.0f;

#pragma unroll
        for (int r = 0; r < 4; ++r) {
            const int gi = gi0 + rb + r;   // <= 767

            float t01 = V1[0] + V1[1], t12 = V1[1] + V1[2], t23 = V1[2] + V1[3];
            float t34 = V1[3] + V1[4], t45 = V1[4] + V1[5], t56 = V1[5] + V1[6];
            float S1v[4] = { t01 + t23 + V1[4], t12 + t34 + V1[5],
                             t23 + t45 + V1[6], t34 + t56 + V1[7] };
            float u01 = V2[0] + V2[1], u12 = V2[1] + V2[2], u23 = V2[2] + V2[3];
            float u34 = V2[3] + V2[4], u45 = V2[4] + V2[5], u56 = V2[5] + V2[6];
            float S2v[4] = { u01 + u23 + V2[4], u12 + u34 + V2[5],
                             u23 + u45 + V2[6], u34 + u56 + V2[7] };

            float cy = (float)(min(gi, HALO) + min(IMG_H - 1 - gi, HALO) + 1);
            float rc[4];
            if (cy == 5.0f) {
#pragma unroll
                for (int c = 0; c < 4; ++c) rc[c] = rcp5[c];
            } else {
#pragma unroll
                for (int c = 0; c < 4; ++c)
                    rc[c] = __fdividef(1.0f, fmaf(cy, cxv[c], -1.0f));
            }

            float pcv[4] = {pv4[r].x, pv4[r].y, pv4[r].z, pv4[r].w};
            float ev[4]  = {ev4[r].x, ev4[r].y, ev4[r].z, ev4[r].w};
            float gv[4]  = {gv4[r].x, gv4[r].y, gv4[r].z, gv4[r].w};
            float wv[4];
#pragma unroll
            for (int c = 0; c < 4; ++c) {
                float pc = pcv[c];
                float C = cy * cxv[c];
                float acc = fmaf(C * pc, pc, fmaf(-2.0f * pc, S1v[c], S2v[c]));
                float cons = fmaf(-acc, rc[c], 1.0f);
                float w = fmaxf(cons * ev[c], gv[c]);
                w = fmaf(w, 0.9f, 0.1f);
                wv[c] = w;
                lsum += w;
            }
            *reinterpret_cast<float4*>(&oimg[(size_t)gi * IMG_W + gj]) =
                make_float4(wv[0], wv[1], wv[2], wv[3]);

            if (r < 3) {   // slide: add row rb+r+5, remove row rb+r (LDS)
                const float* rin  = &pbuf[(rb + r + 5) * LW + c0];
                const float* rout = &pbuf[(rb + r) * LW + c0];
                float4 IA = *reinterpret_cast<const float4*>(rin);
                float4 IB = *reinterpret_cast<const float4*>(rin + 4);
                float4 OA = *reinterpret_cast<const float4*>(rout);
                float4 OB = *reinterpret_cast<const float4*>(rout + 4);
                float vin[8]  = {IA.x, IA.y, IA.z, IA.w, IB.x, IB.y, IB.z, IB.w};
                float vout[8] = {OA.x, OA.y, OA.z, OA.w, OB.x, OB.y, OB.z, OB.w};
#pragma unroll
                for (int cc = 0; cc < 8; ++cc) {
                    V1[cc] += vin[cc] - vout[cc];
                    V2[cc] += fmaf(vin[cc], vin[cc], -(vout[cc] * vout[cc]));
                }
            }
        }

        // ---- 7. per-image sum: wave reduce -> LDS -> one atomic ----
#pragma unroll
        for (int off = 32; off > 0; off >>= 1)
            lsum += __shfl_down(lsum, off, 64);
        if ((tid & 63) == 0) red[tid >> 6] = lsum;
        __syncthreads();   // also orders pbuf reuse for the next iteration
        if (tid == 0)
            atomicAdd(&sums[img], (red[0] + red[1]) + (red[2] + red[3]));

        // ---- advance coords ----
        tile = ntile; img = nimg; gi0 = ngi0; gj0 = ngj0;
    }
}

// Pass 2: divide by per-image mean.
__global__ __launch_bounds__(256) void wk_pass2(
    float* __restrict__ out, const float* __restrict__ sums)
{
    const size_t total4 = (size_t)N_IMG * IMG_H * IMG_W / 4;
    const int per_img4 = IMG_H * IMG_W / 4;   // 147456
    for (size_t i = (size_t)blockIdx.x * blockDim.x + threadIdx.x; i < total4;
         i += (size_t)gridDim.x * blockDim.x) {
        int img = (int)(i / per_img4);
        float scale = (float)(IMG_H * IMG_W) / sums[img];
        float4 v = reinterpret_cast<float4*>(out)[i];
        v.x *= scale; v.y *= scale; v.z *= scale; v.w *= scale;
        reinterpret_cast<float4*>(out)[i] = v;
    }
}

extern "C" void kernel_launch(void* const* d_in, const int* in_sizes, int n_in,
                              void* d_out, int out_size, void* d_ws, size_t ws_size,
                              hipStream_t stream) {
    const float* y_d  = (const float*)d_in[0];
    const float* y_gt = (const float*)d_in[1];
    float* out  = (float*)d_out;
    float* sums = (float*)d_ws;

    hipMemsetAsync(sums, 0, N_IMG * sizeof(float), stream);

    wk_pass1<<<dim3(GRID1), dim3(256), 0, stream>>>(y_d, y_gt, out, sums);
    wk_pass2<<<dim3(2048), dim3(256), 0, stream>>>(out, sums);
}